// Round 6
// baseline (747.544 us; speedup 1.0000x reference)
//
#include <hip/hip_runtime.h>
#include <cstdint>
#include <cstddef>

#define M_DIM 8192
#define N_DIM 4096
#define K_DIM 4096

#define BM 128
#define BN 128
#define BK 128   // i8 elements of K per tile

typedef int int32x4 __attribute__((ext_vector_type(4)));

// ws layout:
//   int32 header (64 KB):
//     [0] = flagA (1 -> stored packed int8, 0 -> widened int32)
//     [1] = flagB
//     [16 .. 16+N)      qb (shifted bias)
//     [16+N .. 16+2N)   int_scale
//     [16+2N .. 16+3N)  frac_bits
//   byte 65536:           A8L (M*K int8, MFMA-fragment-blocked)
//   byte 65536 + M*K:     W8L (N*K int8, MFMA-fragment-blocked)
//
// Blocked layout: fragment f = ((tileRow*32 + kt)*8 + r16)*2 + s is 1 KB at
// offset f*1024; within it byte lane*16+b holds elem[row = r16*16 + (lane&15)]
// [k = kt*128 + s*64 + (lane>>4)*16 + b]  -- exactly the mfma_i32_16x16x64_i8
// A/B operand layout, so the GEMM K-loop is pure coalesced global loads.

typedef __attribute__((address_space(1))) const void* gas_cptr;
typedef __attribute__((address_space(3))) void* las_ptr;

__device__ __forceinline__ void async_copy16(const void* g, void* l) {
    __builtin_amdgcn_global_load_lds((gas_cptr)g, (las_ptr)l, 16, 0, 0);
}

__device__ __forceinline__ int32x4 pack16(const int* p) {
    const int32x4* v = (const int32x4*)p;
    int32x4 w0 = v[0], w1 = v[1], w2 = v[2], w3 = v[3];
    int32x4 r;
    r.x = (w0.x & 0xFF) | ((w0.y & 0xFF) << 8) | ((w0.z & 0xFF) << 16) | (w0.w << 24);
    r.y = (w1.x & 0xFF) | ((w1.y & 0xFF) << 8) | ((w1.z & 0xFF) << 16) | (w1.w << 24);
    r.z = (w2.x & 0xFF) | ((w2.y & 0xFF) << 8) | ((w2.z & 0xFF) << 16) | (w2.w << 24);
    r.w = (w3.x & 0xFF) | ((w3.y & 0xFF) << 8) | ((w3.z & 0xFF) << 16) | (w3.w << 24);
    return r;
}

__global__ void ql_detect_kernel(const int* a, const int* b, int* ws) {
    int t = threadIdx.x;  // 64 threads
    int fa = 0, fb = 0;
    for (int i = t; i < 4096; i += 64) {
        int va = a[i]; if (va > 127 || va < -128) fa = 1;
        int vb = b[i]; if (vb > 127 || vb < -128) fb = 1;
    }
    unsigned long long ba = __ballot(fa);
    unsigned long long bb = __ballot(fb);
    if (t == 0) { ws[0] = ba ? 1 : 0; ws[1] = bb ? 1 : 0; }
}

// Transpose-pack one 128x128 tile into fragment-blocked int8 layout.
// grid: (x = kt = K/128, y = tile row block). LDS-tiled: coalesced reads,
// coalesced 16B writes.
__global__ __launch_bounds__(256)
void ql_blockpack_kernel(const void* src, int8_t* dst, const int* ws, int flag_idx) {
    __shared__ int lds[128 * 36];   // 128 rows x 32 dwords, stride 36 (18 KB)
    const int f8 = __builtin_amdgcn_readfirstlane(ws[flag_idx]);
    const int kt = blockIdx.x;
    const int rb = blockIdx.y;
    const int t  = threadIdx.x;

    if (f8) {
        // packed int8 source: row length K bytes
        const int r0 = t >> 3, c8 = t & 7;
#pragma unroll
        for (int it = 0; it < 4; ++it) {
            const int row = r0 + it * 32;
            int32x4 v = *(const int32x4*)((const int8_t*)src
                         + (size_t)(rb * 128 + row) * K_DIM + kt * 128 + c8 * 16);
            int* p = &lds[row * 36 + c8 * 4];
            p[0] = v.x; p[1] = v.y; p[2] = v.z; p[3] = v.w;
        }
    } else {
        // widened int32 source: row length K ints
        const int r0 = t >> 5, c = t & 31;
#pragma unroll
        for (int it = 0; it < 16; ++it) {
            const int row = r0 + it * 8;
            const int* p = (const int*)src
                         + (size_t)(rb * 128 + row) * K_DIM + kt * 128 + c * 4;
            int32x4 v = *(const int32x4*)p;
            lds[row * 36 + c] = (v.x & 0xFF) | ((v.y & 0xFF) << 8)
                              | ((v.z & 0xFF) << 16) | (v.w << 24);
        }
    }
    __syncthreads();

    // emit 16 KB tile: chunk cI (16 B) -> fragment layout
    const size_t outBase = ((size_t)rb * gridDim.x + kt) * 16384;
#pragma unroll
    for (int rep = 0; rep < 4; ++rep) {
        const int cI  = rep * 256 + t;          // 0..1023
        const int l   = cI & 63;
        const int s   = (cI >> 6) & 1;
        const int r16 = cI >> 7;                // 0..7
        const int qm  = l & 15, qh = l >> 4;
        const int ml  = r16 * 16 + qm;
        const int kdw = s * 16 + qh * 4;
        int32x4 v = *(const int32x4*)&lds[ml * 36 + kdw];
        *(int32x4*)(dst + outBase + (size_t)cI * 16) = v;
    }
}

// Prep from ORIGINAL weight tensor (flag-based): rowsum + requant params.
__global__ void ql_prep_kernel(const void* wptr, const int* qbias,
                               const float* wscale, int* ws) {
    const int lane = threadIdx.x & 63;
    const int wid  = threadIdx.x >> 6;
    const int n = blockIdx.x * 4 + wid;
    const int b8 = __builtin_amdgcn_readfirstlane(ws[1]);

    int s = 0;
    if (b8) {
        const int32x4* row = (const int32x4*)((const int8_t*)wptr + (size_t)n * K_DIM);
        for (int c = lane; c < K_DIM / 16; c += 64) {
            int32x4 v = row[c];
#pragma unroll
            for (int j = 0; j < 4; ++j) {
                int w = (j == 0) ? v.x : (j == 1) ? v.y : (j == 2) ? v.z : v.w;
                s += (int)(int8_t)(w) + (int)(int8_t)(w >> 8)
                   + (int)(int8_t)(w >> 16) + (w >> 24);
            }
        }
    } else {
        const int32x4* row = (const int32x4*)((const int*)wptr + (size_t)n * K_DIM);
        for (int c = lane; c < K_DIM / 4; c += 64) {
            int32x4 v = row[c];
            s += v.x + v.y + v.z + v.w;
        }
    }
#pragma unroll
    for (int off = 32; off > 0; off >>= 1) s += __shfl_down(s, off, 64);

    if (lane == 0) {
        ws[16 + n] = qbias[n] + 3 * s;                       // qbias - rowsum*Zin, Zin=-3
        float folded = (0.05f * wscale[n]) / 0.1f;           // in (0,1)
        int fbits = (int)(7.0f - ceilf(log2f(folded)));
        int isc = (int)rintf(folded * exp2f((float)fbits));  // nearest-even == np.round
        ws[16 + N_DIM + n] = isc;
        ws[16 + 2 * N_DIM + n] = fbits;
    }
}

__device__ __forceinline__ int acc_elem(const int32x4& a, int r) {
    return (r == 0) ? a.x : (r == 1) ? a.y : (r == 2) ? a.z : a.w;
}

// Fast path: fragment-blocked operands, NO LDS / NO barriers in the K-loop.
// Pure coalesced global_load_dwordx4 (L2-resident) interleaved with MFMA,
// software-pipelined one step ahead.
__global__ __launch_bounds__(256)
void ql_gemm_kernel(const int8_t* A8L, const int8_t* W8L, const int* ws, int* out) {
    __shared__ int esc[4 * 16 * 68];   // per-wave epilogue scratch (17.4 KB)

    const int t    = threadIdx.x;
    const int lane = t & 63;
    const int wid  = t >> 6;
    const int bn = blockIdx.x;      // N/128 = 32
    const int bm = blockIdx.y;      // M/128 = 64

    const int wm = (wid >> 1) * 64;
    const int wn = (wid & 1) * 64;
    const int qm = lane & 15;
    const int qh = lane >> 4;

    // wave-fragment base pointers (m16/n16 base = wave offset /16)
    const int8_t* aW = A8L + (size_t)bm * (32 * 16384)
                     + (size_t)((wid >> 1) * 4) * 2048 + lane * 16;
    const int8_t* bW = W8L + (size_t)bn * (32 * 16384)
                     + (size_t)((wid & 1) * 4) * 2048 + lane * 16;

    int32x4 acc[4][4] = {};
    int32x4 af[2][4], bf[2][4];

#pragma unroll
    for (int i = 0; i < 4; ++i) {           // preload step 0
        af[0][i] = *(const int32x4*)(aW + i * 2048);
        bf[0][i] = *(const int32x4*)(bW + i * 2048);
    }

#pragma unroll 2
    for (int st = 0; st < 64; ++st) {       // st = kt*2 + s
        const int cb = st & 1;
        if (st < 63) {
            const int nx = st + 1;
            const size_t off = (size_t)(nx >> 1) * 16384 + (size_t)(nx & 1) * 1024;
#pragma unroll
            for (int i = 0; i < 4; ++i) {
                af[cb ^ 1][i] = *(const int32x4*)(aW + off + i * 2048);
                bf[cb ^ 1][i] = *(const int32x4*)(bW + off + i * 2048);
            }
        }
#pragma unroll
        for (int i = 0; i < 4; ++i)
#pragma unroll
            for (int j = 0; j < 4; ++j)
                acc[i][j] = __builtin_amdgcn_mfma_i32_16x16x64_i8(
                    af[cb][i], bf[cb][j], acc[i][j], 0, 0, 0);
    }

    // ---- epilogue: requantize, per-wave LDS transpose, coalesced stores ----
    const int* qb  = ws + 16;
    const int* isc = ws + 16 + N_DIM;
    const int* fbt = ws + 16 + 2 * N_DIM;
    int* wsc = esc + wid * 1088;            // 16 rows x 68 ints per wave

#pragma unroll
    for (int i = 0; i < 4; ++i) {
#pragma unroll
        for (int j = 0; j < 4; ++j) {
            const int n_g = bn * BN + wn + j * 16 + qm;
            const int b0 = qb[n_g];
            const int s0 = isc[n_g];
            const int f0 = fbt[n_g];
#pragma unroll
            for (int r = 0; r < 4; ++r) {
                int v = acc_elem(acc[i][j], r) + b0;
                long long p = (long long)v * (long long)s0;
                int o = (int)(p >> f0) - 5;            // + OUTPUT_ZERO_POINT (-5)
                o = o < -128 ? -128 : (o > 127 ? 127 : o);
                wsc[(qh * 4 + r) * 68 + j * 16 + qm] = o;
            }
        }
#pragma unroll
        for (int p4 = 0; p4 < 4; ++p4) {
            const int lr = p4 * 4 + qh;
            int32x4 vv = *(const int32x4*)&wsc[lr * 68 + qm * 4];
            const size_t g = (size_t)(bm * BM + wm + i * 16 + lr) * N_DIM
                           + bn * BN + wn + qm * 4;
            *(int32x4*)(out + g) = vv;
        }
    }
}

// Fallback (ws too small): round-3 verified in-loop-pack kernel.
__global__ __launch_bounds__(256)
void ql_gemm_fb_kernel(const void* aptr, const void* bptr, const int* ws, int* out) {
    __shared__ int32x4 Als[BM * BK / 16];
    __shared__ int32x4 Bls[BN * BK / 16];

    const int a8 = __builtin_amdgcn_readfirstlane(ws[0]);
    const int b8 = __builtin_amdgcn_readfirstlane(ws[1]);

    const int t    = threadIdx.x;
    const int lane = t & 63;
    const int wid  = t >> 6;
    const int bn = blockIdx.x;
    const int bm = blockIdx.y;

    const int wm = (wid >> 1) * 64;
    const int wn = (wid & 1) * 64;
    const int qm = lane & 15;
    const int qh = lane >> 4;

    int32x4 acc[4][4] = {};

    for (int kt = 0; kt < K_DIM / BK; ++kt) {
        __syncthreads();
        const int k0 = kt * BK;
#pragma unroll
        for (int r = 0; r < 4; ++r) {
            const int c    = r * 256 + t;
            const int row  = c >> 3;
            const int colg = (c & 7) ^ (row & 7);
            const size_t offA = (size_t)(bm * BM + row) * K_DIM + k0 + colg * 16;
            const size_t offB = (size_t)(bn * BN + row) * K_DIM + k0 + colg * 16;
            if (a8) async_copy16((const int8_t*)aptr + offA, &Als[c]);
            else    Als[c] = pack16((const int*)aptr + offA);
            if (b8) async_copy16((const int8_t*)bptr + offB, &Bls[c]);
            else    Bls[c] = pack16((const int*)bptr + offB);
        }
        __syncthreads();

#pragma unroll
        for (int s = 0; s < 2; ++s) {
            const int colk = s * 4 + qh;
            int32x4 af[4], bf[4];
#pragma unroll
            for (int i = 0; i < 4; ++i) {
                const int ra = wm + i * 16 + qm;
                const int rb = wn + i * 16 + qm;
                af[i] = Als[ra * 8 + (colk ^ (ra & 7))];
                bf[i] = Bls[rb * 8 + (colk ^ (rb & 7))];
            }
#pragma unroll
            for (int i = 0; i < 4; ++i)
#pragma unroll
                for (int j = 0; j < 4; ++j)
                    acc[i][j] = __builtin_amdgcn_mfma_i32_16x16x64_i8(
                        af[i], bf[j], acc[i][j], 0, 0, 0);
        }
    }

    const int* qb  = ws + 16;
    const int* isc = ws + 16 + N_DIM;
    const int* fbt = ws + 16 + 2 * N_DIM;
#pragma unroll
    for (int j = 0; j < 4; ++j) {
        const int n_g = bn * BN + wn + j * 16 + qm;
        const int b0 = qb[n_g];
        const int s0 = isc[n_g];
        const int f0 = fbt[n_g];
#pragma unroll
        for (int i = 0; i < 4; ++i) {
            const int m_base = bm * BM + wm + i * 16 + qh * 4;
#pragma unroll
            for (int r = 0; r < 4; ++r) {
                int v = acc_elem(acc[i][j], r) + b0;
                long long p = (long long)v * (long long)s0;
                int o = (int)(p >> f0) - 5;
                o = o < -128 ? -128 : (o > 127 ? 127 : o);
                out[(size_t)(m_base + r) * N_DIM + n_g] = o;
            }
        }
    }
}

extern "C" void kernel_launch(void* const* d_in, const int* in_sizes, int n_in,
                              void* d_out, int out_size, void* d_ws, size_t ws_size,
                              hipStream_t stream) {
    const void* qin    = d_in[0];
    const void* qwt    = d_in[1];
    const int* qbias   = (const int*)d_in[2];
    const float* wscal = (const float*)d_in[3];
    int* ws  = (int*)d_ws;
    int* out = (int*)d_out;

    hipLaunchKernelGGL(ql_detect_kernel, dim3(1), dim3(64), 0, stream,
                       (const int*)qin, (const int*)qwt, ws);
    hipLaunchKernelGGL(ql_prep_kernel, dim3(N_DIM / 4), dim3(256), 0, stream,
                       qwt, qbias, wscal, ws);

    const size_t need = 65536 + (size_t)M_DIM * K_DIM + (size_t)N_DIM * K_DIM;
    if (ws_size >= need) {
        int8_t* a8l = (int8_t*)d_ws + 65536;
        int8_t* w8l = a8l + (size_t)M_DIM * K_DIM;
        hipLaunchKernelGGL(ql_blockpack_kernel, dim3(K_DIM / 128, M_DIM / 128), dim3(256),
                           0, stream, qin, a8l, ws, 0);
        hipLaunchKernelGGL(ql_blockpack_kernel, dim3(K_DIM / 128, N_DIM / 128), dim3(256),
                           0, stream, qwt, w8l, ws, 1);
        hipLaunchKernelGGL(ql_gemm_kernel, dim3(N_DIM / BN, M_DIM / BM), dim3(256), 0, stream,
                           a8l, w8l, ws, out);
    } else {
        hipLaunchKernelGGL(ql_gemm_fb_kernel, dim3(N_DIM / BN, M_DIM / BM), dim3(256), 0, stream,
                           qin, qwt, ws, out);
    }
}

// Round 7
// 447.512 us; speedup vs baseline: 1.6704x; 1.6704x over previous
//
#include <hip/hip_runtime.h>
#include <cstdint>
#include <cstddef>

#define M_DIM 8192
#define N_DIM 4096
#define K_DIM 4096

#define BM 128
#define BN 128
#define BK 128   // i8 elements of K per tile

typedef int int32x4 __attribute__((ext_vector_type(4)));

// ws layout:
//   int32 header (64 KB):
//     [0] = flagA (1 -> stored packed int8, 0 -> widened int32)
//     [1] = flagB
//     [16 .. 16+N)      rowsum (atomic-accumulated) -> finalized to qb
//     [16+N .. 16+2N)   int_scale
//     [16+2N .. 16+3N)  frac_bits
//   byte 65536:           A8  (M*K int8)
//   byte 65536 + M*K:     W8  (N*K int8)

typedef __attribute__((address_space(1))) const void* gas_cptr;
typedef __attribute__((address_space(3))) void* las_ptr;

__device__ __forceinline__ void async_copy16(const void* g, void* l) {
    __builtin_amdgcn_global_load_lds((gas_cptr)g, (las_ptr)l, 16, 0, 0);
}

__device__ __forceinline__ int32x4 pack16(const int* p) {
    const int32x4* v = (const int32x4*)p;
    int32x4 w0 = v[0], w1 = v[1], w2 = v[2], w3 = v[3];
    int32x4 r;
    r.x = (w0.x & 0xFF) | ((w0.y & 0xFF) << 8) | ((w0.z & 0xFF) << 16) | (w0.w << 24);
    r.y = (w1.x & 0xFF) | ((w1.y & 0xFF) << 8) | ((w1.z & 0xFF) << 16) | (w1.w << 24);
    r.z = (w2.x & 0xFF) | ((w2.y & 0xFF) << 8) | ((w2.z & 0xFF) << 16) | (w2.w << 24);
    r.w = (w3.x & 0xFF) | ((w3.y & 0xFF) << 8) | ((w3.z & 0xFF) << 16) | (w3.w << 24);
    return r;
}

__global__ void ql_detect_kernel(const int* a, const int* b, int* ws) {
    int t = threadIdx.x;  // 64 threads
    int fa = 0, fb = 0;
    for (int i = t; i < 4096; i += 64) {
        int va = a[i]; if (va > 127 || va < -128) fa = 1;
        int vb = b[i]; if (vb > 127 || vb < -128) fb = 1;
    }
    unsigned long long ba = __ballot(fa);
    unsigned long long bb = __ballot(fb);
    if (t == 0) { ws[0] = ba ? 1 : 0; ws[1] = bb ? 1 : 0; }
}

// Merged coalesced repack for both tensors; fuses the W rowsum:
// each wave's 64 consecutive W dwords lie in one row (64 | 1024 dwords/row),
// so one wave-reduce + one atomicAdd per wave accumulates the rowsum.
__global__ __launch_bounds__(256)
void ql_pack2_kernel(const void* asrc, const void* bsrc, int* adst, int* bdst,
                     int* ws, long ndwA, long ndwW) {
    const int fa = __builtin_amdgcn_readfirstlane(ws[0]);
    const int fb = __builtin_amdgcn_readfirstlane(ws[1]);
    const int lane = threadIdx.x & 63;
    const long total = ndwA + ndwW;
    const long stride = (long)gridDim.x * 256;
    for (long c = (long)blockIdx.x * 256 + threadIdx.x; c < total; c += stride) {
        if (c < ndwA) {
            if (fa) adst[c] = ((const int*)asrc)[c];
            else {
                int32x4 v = ((const int32x4*)asrc)[c];
                adst[c] = (v.x & 0xFF) | ((v.y & 0xFF) << 8) | ((v.z & 0xFF) << 16) | (v.w << 24);
            }
        } else {
            long d = c - ndwA;
            int w;
            if (fb) w = ((const int*)bsrc)[d];
            else {
                int32x4 v = ((const int32x4*)bsrc)[d];
                w = (v.x & 0xFF) | ((v.y & 0xFF) << 8) | ((v.z & 0xFF) << 16) | (v.w << 24);
            }
            bdst[d] = w;
            // fused rowsum: byte-sum of this packed dword
            int s = (int)(int8_t)(w) + (int)(int8_t)(w >> 8)
                  + (int)(int8_t)(w >> 16) + (w >> 24);
#pragma unroll
            for (int off = 32; off > 0; off >>= 1) s += __shfl_down(s, off, 64);
            if (lane == 0) {
                const int n = (int)(d >> 10);       // K/4 = 1024 dwords per row
                atomicAdd(&ws[16 + n], s);
            }
        }
    }
}

// Finalize requant params: qb from accumulated rowsum + scale math.
__global__ __launch_bounds__(256)
void ql_finalize_kernel(const int* qbias, const float* wscale, int* ws) {
    const int n = blockIdx.x * 256 + threadIdx.x;
    if (n >= N_DIM) return;
    const int s = ws[16 + n];
    ws[16 + n] = qbias[n] + 3 * s;                       // qbias - rowsum*Zin, Zin=-3
    float folded = (0.05f * wscale[n]) / 0.1f;           // in (0,1)
    int fbits = (int)(7.0f - ceilf(log2f(folded)));
    int isc = (int)rintf(folded * exp2f((float)fbits));  // nearest-even == np.round
    ws[16 + N_DIM + n] = isc;
    ws[16 + 2 * N_DIM + n] = fbits;
}

// Fallback prep (ws too small): reads original W, flag-based, writes qb directly.
__global__ void ql_prep_kernel(const void* wptr, const int* qbias,
                               const float* wscale, int* ws) {
    const int lane = threadIdx.x & 63;
    const int wid  = threadIdx.x >> 6;
    const int n = blockIdx.x * 4 + wid;
    const int b8 = __builtin_amdgcn_readfirstlane(ws[1]);

    int s = 0;
    if (b8) {
        const int32x4* row = (const int32x4*)((const int8_t*)wptr + (size_t)n * K_DIM);
        for (int c = lane; c < K_DIM / 16; c += 64) {
            int32x4 v = row[c];
#pragma unroll
            for (int j = 0; j < 4; ++j) {
                int w = (j == 0) ? v.x : (j == 1) ? v.y : (j == 2) ? v.z : v.w;
                s += (int)(int8_t)(w) + (int)(int8_t)(w >> 8)
                   + (int)(int8_t)(w >> 16) + (w >> 24);
            }
        }
    } else {
        const int32x4* row = (const int32x4*)((const int*)wptr + (size_t)n * K_DIM);
        for (int c = lane; c < K_DIM / 4; c += 64) {
            int32x4 v = row[c];
            s += v.x + v.y + v.z + v.w;
        }
    }
#pragma unroll
    for (int off = 32; off > 0; off >>= 1) s += __shfl_down(s, off, 64);

    if (lane == 0) {
        ws[16 + n] = qbias[n] + 3 * s;
        float folded = (0.05f * wscale[n]) / 0.1f;
        int fbits = (int)(7.0f - ceilf(log2f(folded)));
        int isc = (int)rintf(folded * exp2f((float)fbits));
        ws[16 + N_DIM + n] = isc;
        ws[16 + 2 * N_DIM + n] = fbits;
    }
}

__device__ __forceinline__ int acc_elem(const int32x4& a, int r) {
    return (r == 0) ? a.x : (r == 1) ? a.y : (r == 2) ? a.z : a.w;
}

// Verified round-3 fast path: int8 sources, global_load_lds staging,
// XOR-swizzled LDS, scattered epilogue. 180 us / absmax 0.
__global__ __launch_bounds__(256)
void ql_gemm_kernel(const int8_t* aptr, const int8_t* bptr, const int* ws, int* out) {
    __shared__ int32x4 Als[BM * BK / 16];   // 16 KB
    __shared__ int32x4 Bls[BN * BK / 16];   // 16 KB

    const int t    = threadIdx.x;
    const int lane = t & 63;
    const int wid  = t >> 6;
    const int bn = blockIdx.x;      // N/128 = 32
    const int bm = blockIdx.y;      // M/128 = 64

    const int wm = (wid >> 1) * 64;
    const int wn = (wid & 1) * 64;
    const int qm = lane & 15;
    const int qh = lane >> 4;

    int32x4 acc[4][4] = {};

    for (int kt = 0; kt < K_DIM / BK; ++kt) {
        __syncthreads();
        const int k0 = kt * BK;
#pragma unroll
        for (int r = 0; r < 4; ++r) {
            const int c    = r * 256 + t;                 // LDS chunk id 0..1023
            const int row  = c >> 3;
            const int colg = (c & 7) ^ (row & 7);         // inverse swizzle on source
            const size_t offA = (size_t)(bm * BM + row) * K_DIM + k0 + colg * 16;
            const size_t offB = (size_t)(bn * BN + row) * K_DIM + k0 + colg * 16;
            async_copy16(aptr + offA, &Als[c]);
            async_copy16(bptr + offB, &Bls[c]);
        }
        __syncthreads();

#pragma unroll
        for (int s = 0; s < 2; ++s) {
            const int colk = s * 4 + qh;                  // k-chunk 0..7 within BK
            int32x4 af[4], bf[4];
#pragma unroll
            for (int i = 0; i < 4; ++i) {
                const int ra = wm + i * 16 + qm;
                const int rb = wn + i * 16 + qm;
                af[i] = Als[ra * 8 + (colk ^ (ra & 7))];
                bf[i] = Bls[rb * 8 + (colk ^ (rb & 7))];
            }
#pragma unroll
            for (int i = 0; i < 4; ++i)
#pragma unroll
                for (int j = 0; j < 4; ++j)
                    acc[i][j] = __builtin_amdgcn_mfma_i32_16x16x64_i8(
                        af[i], bf[j], acc[i][j], 0, 0, 0);
        }
    }

    const int* qb  = ws + 16;
    const int* isc = ws + 16 + N_DIM;
    const int* fbt = ws + 16 + 2 * N_DIM;
#pragma unroll
    for (int j = 0; j < 4; ++j) {
        const int n_g = bn * BN + wn + j * 16 + qm;
        const int b0 = qb[n_g];
        const int s0 = isc[n_g];
        const int f0 = fbt[n_g];
#pragma unroll
        for (int i = 0; i < 4; ++i) {
            const int m_base = bm * BM + wm + i * 16 + qh * 4;
#pragma unroll
            for (int r = 0; r < 4; ++r) {
                int v = acc_elem(acc[i][j], r) + b0;
                long long p = (long long)v * (long long)s0;
                int o = (int)(p >> f0) - 5;            // + OUTPUT_ZERO_POINT (-5)
                o = o < -128 ? -128 : (o > 127 ? 127 : o);
                out[(size_t)(m_base + r) * N_DIM + n_g] = o;
            }
        }
    }
}

// Fallback (ws too small): packs in-loop (round-3 verified).
__global__ __launch_bounds__(256)
void ql_gemm_fb_kernel(const void* aptr, const void* bptr, const int* ws, int* out) {
    __shared__ int32x4 Als[BM * BK / 16];
    __shared__ int32x4 Bls[BN * BK / 16];

    const int a8 = __builtin_amdgcn_readfirstlane(ws[0]);
    const int b8 = __builtin_amdgcn_readfirstlane(ws[1]);

    const int t    = threadIdx.x;
    const int lane = t & 63;
    const int wid  = t >> 6;
    const int bn = blockIdx.x;
    const int bm = blockIdx.y;

    const int wm = (wid >> 1) * 64;
    const int wn = (wid & 1) * 64;
    const int qm = lane & 15;
    const int qh = lane >> 4;

    int32x4 acc[4][4] = {};

    for (int kt = 0; kt < K_DIM / BK; ++kt) {
        __syncthreads();
        const int k0 = kt * BK;
#pragma unroll
        for (int r = 0; r < 4; ++r) {
            const int c    = r * 256 + t;
            const int row  = c >> 3;
            const int colg = (c & 7) ^ (row & 7);
            const size_t offA = (size_t)(bm * BM + row) * K_DIM + k0 + colg * 16;
            const size_t offB = (size_t)(bn * BN + row) * K_DIM + k0 + colg * 16;
            if (a8) async_copy16((const int8_t*)aptr + offA, &Als[c]);
            else    Als[c] = pack16((const int*)aptr + offA);
            if (b8) async_copy16((const int8_t*)bptr + offB, &Bls[c]);
            else    Bls[c] = pack16((const int*)bptr + offB);
        }
        __syncthreads();

#pragma unroll
        for (int s = 0; s < 2; ++s) {
            const int colk = s * 4 + qh;
            int32x4 af[4], bf[4];
#pragma unroll
            for (int i = 0; i < 4; ++i) {
                const int ra = wm + i * 16 + qm;
                const int rb = wn + i * 16 + qm;
                af[i] = Als[ra * 8 + (colk ^ (ra & 7))];
                bf[i] = Bls[rb * 8 + (colk ^ (rb & 7))];
            }
#pragma unroll
            for (int i = 0; i < 4; ++i)
#pragma unroll
                for (int j = 0; j < 4; ++j)
                    acc[i][j] = __builtin_amdgcn_mfma_i32_16x16x64_i8(
                        af[i], bf[j], acc[i][j], 0, 0, 0);
        }
    }

    const int* qb  = ws + 16;
    const int* isc = ws + 16 + N_DIM;
    const int* fbt = ws + 16 + 2 * N_DIM;
#pragma unroll
    for (int j = 0; j < 4; ++j) {
        const int n_g = bn * BN + wn + j * 16 + qm;
        const int b0 = qb[n_g];
        const int s0 = isc[n_g];
        const int f0 = fbt[n_g];
#pragma unroll
        for (int i = 0; i < 4; ++i) {
            const int m_base = bm * BM + wm + i * 16 + qh * 4;
#pragma unroll
            for (int r = 0; r < 4; ++r) {
                int v = acc_elem(acc[i][j], r) + b0;
                long long p = (long long)v * (long long)s0;
                int o = (int)(p >> f0) - 5;
                o = o < -128 ? -128 : (o > 127 ? 127 : o);
                out[(size_t)(m_base + r) * N_DIM + n_g] = o;
            }
        }
    }
}

extern "C" void kernel_launch(void* const* d_in, const int* in_sizes, int n_in,
                              void* d_out, int out_size, void* d_ws, size_t ws_size,
                              hipStream_t stream) {
    const void* qin    = d_in[0];
    const void* qwt    = d_in[1];
    const int* qbias   = (const int*)d_in[2];
    const float* wscal = (const float*)d_in[3];
    int* ws  = (int*)d_ws;
    int* out = (int*)d_out;

    hipLaunchKernelGGL(ql_detect_kernel, dim3(1), dim3(64), 0, stream,
                       (const int*)qin, (const int*)qwt, ws);

    const size_t need = 65536 + (size_t)M_DIM * K_DIM + (size_t)N_DIM * K_DIM;
    if (ws_size >= need) {
        int8_t* a8 = (int8_t*)d_ws + 65536;
        int8_t* w8 = a8 + (size_t)M_DIM * K_DIM;
        const long ndwA = (long)M_DIM * K_DIM / 4;
        const long ndwW = (long)N_DIM * K_DIM / 4;
        // zero the rowsum accumulators (ws is poisoned 0xAA each call)
        hipMemsetAsync(ws + 16, 0, N_DIM * sizeof(int), stream);
        hipLaunchKernelGGL(ql_pack2_kernel, dim3((unsigned)((ndwA + ndwW) / (256 * 4))),
                           dim3(256), 0, stream,
                           qin, qwt, (int*)a8, (int*)w8, ws, ndwA, ndwW);
        hipLaunchKernelGGL(ql_finalize_kernel, dim3((N_DIM + 255) / 256), dim3(256),
                           0, stream, qbias, wscal, ws);
        hipLaunchKernelGGL(ql_gemm_kernel, dim3(N_DIM / BN, M_DIM / BM), dim3(256), 0, stream,
                           a8, w8, ws, out);
    } else {
        hipLaunchKernelGGL(ql_prep_kernel, dim3(N_DIM / 4), dim3(256), 0, stream,
                           qwt, qbias, wscal, ws);
        hipLaunchKernelGGL(ql_gemm_fb_kernel, dim3(N_DIM / BN, M_DIM / BM), dim3(256), 0, stream,
                           qin, qwt, ws, out);
    }
}